// Round 5
// baseline (1554.414 us; speedup 1.0000x reference)
//
#include <hip/hip_runtime.h>
#include <cstddef>
#include <cstdint>

#define N_NODES 102400
#define N_EDGES 3276800
#define N_GRAPHS 1024
#define NBUCK 400            // node >> 8 -> 400 buckets of 256 nodes

typedef unsigned short ushortT;
typedef unsigned int uintT;

__device__ __forceinline__ float b2f(ushortT h) {
    return __uint_as_float(((uintT)h) << 16);
}
__device__ __forceinline__ ushortT f2b(float f) {
    uintT u = __float_as_uint(f);
    uintT r = (u + 0x7fffu + ((u >> 16) & 1u)) >> 16;
    return (ushortT)r;
}

// ---------------------------------------------------------------------------
// Pass A: per-block LDS histograms of dst/src coarse buckets -> global counts
// 256 blocks x 12800 edges each (exactly covers 3,276,800)
// ---------------------------------------------------------------------------
__global__ __launch_bounds__(256) void k_binA(const int* __restrict__ src,
                                              const int* __restrict__ dst,
                                              int* __restrict__ binCntD,
                                              int* __restrict__ binCntS) {
    __shared__ int hd[NBUCK], hs[NBUCK];
    int t = threadIdx.x;
    for (int i = t; i < NBUCK; i += 256) { hd[i] = 0; hs[i] = 0; }
    __syncthreads();
    int base = blockIdx.x * 12800;
    for (int k = 0; k < 50; k++) {
        int e = base + k * 256 + t;
        atomicAdd(&hd[dst[e] >> 8], 1);
        atomicAdd(&hs[src[e] >> 8], 1);
    }
    __syncthreads();
    for (int i = t; i < NBUCK; i += 256) {
        if (hd[i]) atomicAdd(&binCntD[i], hd[i]);
        if (hs[i]) atomicAdd(&binCntS[i], hs[i]);
    }
}

// Tiny serial scans over 400 bucket counts (one thread each, separate waves)
__global__ void k_scanBins(const int* __restrict__ binCntD, const int* __restrict__ binCntS,
                           int* __restrict__ binBaseD, int* __restrict__ binBaseS,
                           int* __restrict__ cursorD, int* __restrict__ cursorS,
                           int* __restrict__ rowp) {
    int t = threadIdx.x;
    if (t == 0) {
        int run = 0;
        for (int i = 0; i < NBUCK; i++) {
            binBaseD[i] = run; cursorD[i] = run; run += binCntD[i];
        }
        binBaseD[NBUCK] = run;
        rowp[N_NODES] = run;       // == N_EDGES
    } else if (t == 64) {
        int run = 0;
        for (int i = 0; i < NBUCK; i++) {
            binBaseS[i] = run; cursorS[i] = run; run += binCntS[i];
        }
        binBaseS[NBUCK] = run;
    }
}

// ---------------------------------------------------------------------------
// Pass B: place edges into dst-bucket regions (edsD) and src-bucket regions
// (edsS). Block claims per-bucket ranges with ONE global atomic per
// (block,bucket); per-edge placement via LDS cursors.
// edsD: x = (src<<8)|dstLow (25 bits), y = attr bits
// edsS: x = srcLow, y = attr bits
// ---------------------------------------------------------------------------
__global__ __launch_bounds__(256) void k_binB(const int* __restrict__ src,
                                              const int* __restrict__ dst,
                                              const float* __restrict__ attr,
                                              int* __restrict__ cursorD,
                                              int* __restrict__ cursorS,
                                              int2* __restrict__ edsD,
                                              int2* __restrict__ edsS) {
    __shared__ int hd[NBUCK], hs[NBUCK];
    int t = threadIdx.x;
    for (int i = t; i < NBUCK; i += 256) { hd[i] = 0; hs[i] = 0; }
    __syncthreads();
    int base = blockIdx.x * 12800;
    for (int k = 0; k < 50; k++) {
        int e = base + k * 256 + t;
        atomicAdd(&hd[dst[e] >> 8], 1);
        atomicAdd(&hs[src[e] >> 8], 1);
    }
    __syncthreads();
    for (int i = t; i < NBUCK; i += 256) {
        int c = hd[i];
        hd[i] = c ? atomicAdd(&cursorD[i], c) : 0;
        c = hs[i];
        hs[i] = c ? atomicAdd(&cursorS[i], c) : 0;
    }
    __syncthreads();
    for (int k = 0; k < 50; k++) {
        int e = base + k * 256 + t;
        int s = src[e], d = dst[e];
        int a = __float_as_int(attr[e]);
        int p = atomicAdd(&hd[d >> 8], 1);
        edsD[p] = make_int2((s << 8) | (d & 255), a);
        int q = atomicAdd(&hs[s >> 8], 1);
        edsS[q] = make_int2(s & 255, a);
    }
}

// ---------------------------------------------------------------------------
// Per-bucket weighted degree via LDS float atomics -> dinv
// ---------------------------------------------------------------------------
__global__ __launch_bounds__(256) void k_deg(const int2* __restrict__ edsS,
                                             const int* __restrict__ binBaseS,
                                             float* __restrict__ dinv) {
    __shared__ float degL[256];
    int b = blockIdx.x, t = threadIdx.x;
    degL[t] = 0.f;
    __syncthreads();
    int s0 = binBaseS[b], s1 = binBaseS[b + 1];
    for (int i = s0 + t; i < s1; i += 256) {
        int2 e = edsS[i];
        atomicAdd(&degL[e.x], __int_as_float(e.y));
    }
    __syncthreads();
    float d = degL[t];
    dinv[b * 256 + t] = d > 0.f ? rsqrtf(d) : 0.f;
}

// ---------------------------------------------------------------------------
// Per-bucket exact CSR: LDS count -> LDS scan -> rowp; place edges grouped by
// node with LDS cursors. cedge weight = -attr * dinv[dst]  (dinv[src] is
// folded into the bf16 gather tables).
// ---------------------------------------------------------------------------
__global__ __launch_bounds__(256) void k_csr(const int2* __restrict__ edsD,
                                             const int* __restrict__ binBaseD,
                                             const float* __restrict__ dinv,
                                             int* __restrict__ rowp,
                                             int2* __restrict__ cedge) {
    __shared__ int cntL[256];
    __shared__ int curL[256];
    __shared__ float dL[256];
    int b = blockIdx.x, t = threadIdx.x;
    cntL[t] = 0;
    dL[t] = dinv[b * 256 + t];
    __syncthreads();
    int s0 = binBaseD[b], s1 = binBaseD[b + 1];
    for (int i = s0 + t; i < s1; i += 256) {
        atomicAdd(&cntL[edsD[i].x & 255], 1);
    }
    __syncthreads();
    int v = cntL[t];
    for (int o = 1; o < 256; o <<= 1) {          // inclusive Hillis-Steele
        int x = (t >= o) ? cntL[t - o] : 0;
        __syncthreads();
        cntL[t] += x;
        __syncthreads();
    }
    int excl = cntL[t] - v;
    curL[t] = s0 + excl;
    rowp[b * 256 + t] = s0 + excl;
    __syncthreads();
    for (int i = s0 + t; i < s1; i += 256) {
        int2 e = edsD[i];
        int dl = e.x & 255;
        float w = -__int_as_float(e.y) * dL[dl];
        int p = atomicAdd(&curL[dl], 1);
        cedge[p] = make_int2(e.x >> 8, __float_as_int(w));
    }
}

// Wcat = [W0 - W2 | W1 | W2]  (fin x 192) from w[3][fin][64]
__global__ void k_wcat(const float* __restrict__ w, float* __restrict__ wcat, int fin) {
    int i = blockIdx.x * blockDim.x + threadIdx.x;
    if (i >= fin * 192) return;
    int r = i / 192, j = i % 192;
    int k = j >> 6, jj = j & 63;
    float v = w[(size_t)k * fin * 64 + r * 64 + jj];
    if (k == 0) v -= w[(size_t)2 * fin * 64 + r * 64 + jj];
    wcat[i] = v;
}

// ---------------------------------------------------------------------------
// SpMM: gathers bf16 rows (tables hold dinv[n]*X[n], stride 64), fp32 acc,
// fully-pipelined clamped unroll-8 (no serial tail).
// MODE 0: r = acc          MODE 1: r = Aux + 2*acc
// MODE 2: r = 2*acc - Aux  MODE 3: r = relu(Aux + acc + bias[lane])
// WB: also write bf16 mirror of dinv[node]*r.
// ---------------------------------------------------------------------------
template <int MODE, int SY, int SA, bool WB>
__global__ __launch_bounds__(256) void k_spmm(const int* __restrict__ rowp,
                                              const int2* __restrict__ cedge,
                                              const ushortT* __restrict__ Xb,
                                              float* __restrict__ Y,
                                              const float* __restrict__ Aux,
                                              const float* __restrict__ bias,
                                              ushortT* __restrict__ Yb,
                                              const float* __restrict__ dinv) {
    int node = blockIdx.x * 4 + (threadIdx.x >> 6);
    int lane = threadIdx.x & 63;
    int s = rowp[node], e = rowp[node + 1];
    float acc = 0.f;
    for (int i = s; i < e; i += 8) {
        int2 ed[8];
        float v[8];
#pragma unroll
        for (int u = 0; u < 8; u++) {
            int idx = min(i + u, e - 1);
            ed[u] = cedge[idx];
        }
#pragma unroll
        for (int u = 0; u < 8; u++) v[u] = b2f(Xb[(size_t)ed[u].x * 64 + lane]);
#pragma unroll
        for (int u = 0; u < 8; u++) {
            float w = (i + u < e) ? __int_as_float(ed[u].y) : 0.f;
            acc = fmaf(w, v[u], acc);
        }
    }
    float r;
    if (MODE == 0)      r = acc;
    else if (MODE == 1) r = Aux[(size_t)node * SA + lane] + 2.f * acc;
    else if (MODE == 2) r = 2.f * acc - Aux[(size_t)node * SA + lane];
    else                r = fmaxf(Aux[(size_t)node * SA + lane] + acc + bias[lane], 0.f);
    Y[(size_t)node * SY + lane] = r;
    if (WB) Yb[(size_t)node * 64 + lane] = f2b(r * dinv[node]);
}

// ---------------------------------------------------------------------------
// GEMM: out[n, colOff + 0..63] = X[n,:] @ W[:, colOff..] (+bias, relu)
// BSLOT >= 0: blocks with colOff == BSLOT write a bf16 mirror of dinv[n]*acc.
// ---------------------------------------------------------------------------
template <int FIN, int SX, int FTOT, int SOUT, bool RELU, int BSLOT>
__global__ __launch_bounds__(128) void k_gemm(const float* __restrict__ X,
                                              const float* __restrict__ W,
                                              const float* __restrict__ bias,
                                              float* __restrict__ out,
                                              ushortT* __restrict__ bout,
                                              const float* __restrict__ dinv) {
    constexpr int KC = 16;
    __shared__ float Xs[KC][129];
    int t = threadIdx.x;
    int nodeBase = blockIdx.x * 128;
    int colOff = blockIdx.y * 64;
    float acc[64];
#pragma unroll
    for (int j = 0; j < 64; j++) acc[j] = 0.f;
    int kk = t & 15, nl0 = t >> 4;
    for (int k0 = 0; k0 < FIN; k0 += KC) {
        __syncthreads();
#pragma unroll
        for (int r = 0; r < 16; r++) {
            int nl = nl0 + r * 8;
            Xs[kk][nl] = X[(size_t)(nodeBase + nl) * SX + k0 + kk];
        }
        __syncthreads();
#pragma unroll
        for (int i = 0; i < KC; i++) {
            float xv = Xs[i][t];
            const float* wr = W + (size_t)(k0 + i) * FTOT + colOff;
#pragma unroll
            for (int j = 0; j < 64; j++) acc[j] = fmaf(xv, wr[j], acc[j]);
        }
    }
    size_t obase = (size_t)(nodeBase + t) * SOUT + colOff;
    float4* outv = reinterpret_cast<float4*>(out + obase);
#pragma unroll
    for (int j = 0; j < 16; j++) {
        float4 v;
        if (RELU) {
            v.x = fmaxf(acc[4 * j + 0] + bias[colOff + 4 * j + 0], 0.f);
            v.y = fmaxf(acc[4 * j + 1] + bias[colOff + 4 * j + 1], 0.f);
            v.z = fmaxf(acc[4 * j + 2] + bias[colOff + 4 * j + 2], 0.f);
            v.w = fmaxf(acc[4 * j + 3] + bias[colOff + 4 * j + 3], 0.f);
        } else {
            v.x = acc[4 * j + 0]; v.y = acc[4 * j + 1];
            v.z = acc[4 * j + 2]; v.w = acc[4 * j + 3];
        }
        outv[j] = v;
    }
    if (BSLOT >= 0 && colOff == BSLOT) {
        float dv = dinv[nodeBase + t];
        ushort4* bv = reinterpret_cast<ushort4*>(bout + (size_t)(nodeBase + t) * 64);
#pragma unroll
        for (int j = 0; j < 16; j++) {
            ushort4 h;
            h.x = f2b(acc[4 * j + 0] * dv);
            h.y = f2b(acc[4 * j + 1] * dv);
            h.z = f2b(acc[4 * j + 2] * dv);
            h.w = f2b(acc[4 * j + 3] * dv);
            bv[j] = h;
        }
    }
}

// ---------------------------------------------------------------------------
// Pooling: 64 consecutive nodes per block (batch sorted -> run-length)
// ---------------------------------------------------------------------------
__global__ __launch_bounds__(128) void k_pool(const int* __restrict__ batch,
                                              const float* __restrict__ H3,
                                              float* __restrict__ pooled,
                                              float* __restrict__ gcnt) {
    int t = threadIdx.x;
    int n0 = blockIdx.x * 64;
    int g = batch[n0];
    float a = 0.f;
    int c = 0;
    for (int k = 0; k < 64; k++) {
        int gn = batch[n0 + k];
        if (gn != g) {
            atomicAdd(&pooled[(size_t)g * 128 + t], a);
            if (t == 0) atomicAdd(&gcnt[g], (float)c);
            g = gn; a = 0.f; c = 0;
        }
        a += H3[(size_t)(n0 + k) * 128 + t];
        c++;
    }
    atomicAdd(&pooled[(size_t)g * 128 + t], a);
    if (t == 0) atomicAdd(&gcnt[g], (float)c);
}

__global__ void k_final(const float* __restrict__ pooled, const float* __restrict__ gcnt,
                        const float* __restrict__ lin_w, const float* __restrict__ lin_b,
                        float* __restrict__ out) {
    int g = blockIdx.x * 4 + (threadIdx.x >> 6);
    int lane = threadIdx.x & 63;
    if (g >= N_GRAPHS) return;
    float inv = 1.f / fmaxf(gcnt[g], 1.f);
    float v0 = pooled[(size_t)g * 128 + lane] * inv;
    float v1 = pooled[(size_t)g * 128 + 64 + lane] * inv;
    float p0 = v0 * lin_w[lane * 2 + 0] + v1 * lin_w[(lane + 64) * 2 + 0];
    float p1 = v0 * lin_w[lane * 2 + 1] + v1 * lin_w[(lane + 64) * 2 + 1];
    for (int o = 32; o > 0; o >>= 1) {
        p0 += __shfl_down(p0, o);
        p1 += __shfl_down(p1, o);
    }
    if (lane == 0) {
        out[g * 2 + 0] = p0 + lin_b[0];
        out[g * 2 + 1] = p1 + lin_b[1];
    }
}

// ---------------------------------------------------------------------------
extern "C" void kernel_launch(void* const* d_in, const int* in_sizes, int n_in,
                              void* d_out, int out_size, void* d_ws, size_t ws_size,
                              hipStream_t stream) {
    const float* x     = (const float*)d_in[0];
    const int*   src   = (const int*)d_in[1];
    const int*   dst   = src + N_EDGES;
    const float* eattr = (const float*)d_in[2];
    const int*   batch = (const int*)d_in[3];
    const float* w1    = (const float*)d_in[4];
    const float* b1    = (const float*)d_in[5];
    const float* w2    = (const float*)d_in[6];
    const float* b2    = (const float*)d_in[7];
    const float* w3    = (const float*)d_in[8];
    const float* b3    = (const float*)d_in[9];
    const float* lin_w = (const float*)d_in[10];
    const float* lin_b = (const float*)d_in[11];
    float* out = (float*)d_out;

    char* ws = (char*)d_ws;
    size_t off = 0;
    auto alloc = [&](size_t bytes) -> char* {
        char* p = ws + off;
        off += (bytes + 255) & ~(size_t)255;
        return p;
    };
    int*   binCntD  = (int*)  alloc(NBUCK * 4 * 2);           // D and S contiguous
    int*   binCntS  = binCntD + NBUCK;
    int*   binBaseD = (int*)  alloc((NBUCK + 1) * 4);
    int*   binBaseS = (int*)  alloc((NBUCK + 1) * 4);
    int*   cursorD  = (int*)  alloc(NBUCK * 4);
    int*   cursorS  = (int*)  alloc(NBUCK * 4);
    float* dinv     = (float*)alloc((size_t)N_NODES * 4);
    int*   rowp     = (int*)  alloc((size_t)(N_NODES + 1) * 4);
    float* wcat1    = (float*)alloc(128 * 192 * 4);
    float* wcat2    = (float*)alloc(64 * 192 * 4);
    float* pooled   = (float*)alloc((size_t)(N_GRAPHS * 128 + N_GRAPHS) * 4);
    float* gcnt     = pooled + (size_t)N_GRAPHS * 128;
    int2*  cedge    = (int2*) alloc((size_t)N_EDGES * 8);      // 26.2 MB
    float* P        = (float*)alloc((size_t)N_NODES * 192 * 4); // 78.6 MB
    float* H        = (float*)alloc((size_t)N_NODES * 128 * 4); // 52.4 MB
    // transient binned-edge arrays alias P (dead before the first GEMM writes P)
    int2* edsD = (int2*)P;                        // 26.2 MB
    int2* edsS = edsD + (size_t)N_EDGES;          // 26.2 MB (52.4 < 78.6 OK)
    // bf16 gather tables alias H's upper half (dead before layer-3 GEMM writes H3)
    ushortT* G0 = (ushortT*)(H + (size_t)N_NODES * 64);        // 13.1 MB
    ushortT* G1 = G0 + (size_t)N_NODES * 64;                   // 13.1 MB

    hipMemsetAsync(binCntD, 0, NBUCK * 4 * 2, stream);
    hipMemsetAsync(pooled, 0, (size_t)(N_GRAPHS * 128 + N_GRAPHS) * 4, stream);

    // ---- Atomic-light CSR build
    k_binA<<<256, 256, 0, stream>>>(src, dst, binCntD, binCntS);
    k_scanBins<<<1, 128, 0, stream>>>(binCntD, binCntS, binBaseD, binBaseS,
                                      cursorD, cursorS, rowp);
    k_binB<<<256, 256, 0, stream>>>(src, dst, eattr, cursorD, cursorS, edsD, edsS);
    k_deg<<<NBUCK, 256, 0, stream>>>(edsS, binBaseS, dinv);
    k_csr<<<NBUCK, 256, 0, stream>>>(edsD, binBaseD, dinv, rowp, cedge);

    // concatenated weights for project-first layers
    k_wcat<<<(128 * 192 + 255) / 256, 256, 0, stream>>>(w1, wcat1, 128);
    k_wcat<<<(64 * 192 + 255) / 256, 256, 0, stream>>>(w2, wcat2, 64);

    // ---- Layer 1 (128 -> 64): P = x @ [W0-W2|W1|W2], mirror dinv*P2 -> G0
    k_gemm<128, 128, 192, 192, false, 128><<<dim3(800, 3), 128, 0, stream>>>(x, wcat1, nullptr, P, G0, dinv);
    // Q = P1 + 2*L*P2 -> P+64 (fp32) and G1 (bf16, dinv-folded)
    k_spmm<1, 192, 192, true><<<N_NODES / 4, 256, 0, stream>>>(rowp, cedge, G0, P + 64, P + 64, nullptr, G1, dinv);
    // H1 = relu(P0c + L*Q + b1) -> H (stride 64)
    k_spmm<3, 64, 192, false><<<N_NODES / 4, 256, 0, stream>>>(rowp, cedge, G1, H, P, b1, nullptr, dinv);

    // ---- Layer 2 (64 -> 64)
    k_gemm<64, 64, 192, 192, false, 128><<<dim3(800, 3), 128, 0, stream>>>(H, wcat2, nullptr, P, G0, dinv);
    k_spmm<1, 192, 192, true><<<N_NODES / 4, 256, 0, stream>>>(rowp, cedge, G0, P + 64, P + 64, nullptr, G1, dinv);
    // T0 = relu(...) -> P slot0 (fp32) and G0 (bf16, dinv-folded)
    k_spmm<3, 192, 192, true><<<N_NODES / 4, 256, 0, stream>>>(rowp, cedge, G1, P, P, b2, G0, dinv);

    // ---- Layer 3 (64 -> 128), spmm-first
    // T1 = L*T0 -> P+64 (fp32) and G1 (bf16, dinv-folded)
    k_spmm<0, 192, 192, true><<<N_NODES / 4, 256, 0, stream>>>(rowp, cedge, G0, P + 64, P, nullptr, G1, dinv);
    // T2 = 2*L*T1 - T0 -> P+128
    k_spmm<2, 192, 192, false><<<N_NODES / 4, 256, 0, stream>>>(rowp, cedge, G1, P + 128, P, nullptr, nullptr, dinv);
    // H3 = relu([T0|T1|T2] @ w3_flat + b3) -> H (clobbers G0/G1 - dead)
    k_gemm<192, 192, 128, 128, true, -1><<<dim3(800, 2), 128, 0, stream>>>(P, w3, b3, H, nullptr, dinv);

    // ---- Pool + final linear
    k_pool<<<N_NODES / 64, 128, 0, stream>>>(batch, H, pooled, gcnt);
    k_final<<<N_GRAPHS / 4, 256, 0, stream>>>(pooled, gcnt, lin_w, lin_b, out);
}

// Round 6
// 1456.067 us; speedup vs baseline: 1.0675x; 1.0675x over previous
//
#include <hip/hip_runtime.h>
#include <cstddef>
#include <cstdint>

#define N_NODES 102400
#define N_EDGES 3276800
#define N_GRAPHS 1024
#define NBUCK 400            // node >> 8 -> 400 buckets of 256 nodes
#define N64 ((size_t)N_NODES * 64)

typedef unsigned short ushortT;
typedef unsigned int uintT;
typedef __attribute__((ext_vector_type(8))) short bf16x8;
typedef __attribute__((ext_vector_type(4))) float f32x4;

__device__ __forceinline__ float b2f(ushortT h) {
    return __uint_as_float(((uintT)h) << 16);
}
__device__ __forceinline__ ushortT f2b(float f) {
    uintT u = __float_as_uint(f);
    uintT r = (u + 0x7fffu + ((u >> 16) & 1u)) >> 16;
    return (ushortT)r;
}

// ---------------------------------------------------------------------------
// Pass A: per-block LDS histograms of dst/src coarse buckets -> global counts
// ---------------------------------------------------------------------------
__global__ __launch_bounds__(256) void k_binA(const int* __restrict__ src,
                                              const int* __restrict__ dst,
                                              int* __restrict__ binCntD,
                                              int* __restrict__ binCntS) {
    __shared__ int hd[NBUCK], hs[NBUCK];
    int t = threadIdx.x;
    for (int i = t; i < NBUCK; i += 256) { hd[i] = 0; hs[i] = 0; }
    __syncthreads();
    int base = blockIdx.x * 12800;
    for (int k = 0; k < 50; k++) {
        int e = base + k * 256 + t;
        atomicAdd(&hd[dst[e] >> 8], 1);
        atomicAdd(&hs[src[e] >> 8], 1);
    }
    __syncthreads();
    for (int i = t; i < NBUCK; i += 256) {
        if (hd[i]) atomicAdd(&binCntD[i], hd[i]);
        if (hs[i]) atomicAdd(&binCntS[i], hs[i]);
    }
}

__global__ void k_scanBins(const int* __restrict__ binCntD, const int* __restrict__ binCntS,
                           int* __restrict__ binBaseD, int* __restrict__ binBaseS,
                           int* __restrict__ cursorD, int* __restrict__ cursorS,
                           int* __restrict__ rowp) {
    int t = threadIdx.x;
    if (t == 0) {
        int run = 0;
        for (int i = 0; i < NBUCK; i++) {
            binBaseD[i] = run; cursorD[i] = run; run += binCntD[i];
        }
        binBaseD[NBUCK] = run;
        rowp[N_NODES] = run;
    } else if (t == 64) {
        int run = 0;
        for (int i = 0; i < NBUCK; i++) {
            binBaseS[i] = run; cursorS[i] = run; run += binCntS[i];
        }
        binBaseS[NBUCK] = run;
    }
}

// ---------------------------------------------------------------------------
// Pass B: place edges into dst-bucket regions (edsD) and src-bucket regions
// (edsS). One global atomic per (block,bucket); per-edge via LDS cursors.
// edsD: x = (src<<8)|dstLow, y = attr bits.  edsS: x = srcLow, y = attr bits
// ---------------------------------------------------------------------------
__global__ __launch_bounds__(256) void k_binB(const int* __restrict__ src,
                                              const int* __restrict__ dst,
                                              const float* __restrict__ attr,
                                              int* __restrict__ cursorD,
                                              int* __restrict__ cursorS,
                                              int2* __restrict__ edsD,
                                              int2* __restrict__ edsS) {
    __shared__ int hd[NBUCK], hs[NBUCK];
    int t = threadIdx.x;
    for (int i = t; i < NBUCK; i += 256) { hd[i] = 0; hs[i] = 0; }
    __syncthreads();
    int base = blockIdx.x * 12800;
    for (int k = 0; k < 50; k++) {
        int e = base + k * 256 + t;
        atomicAdd(&hd[dst[e] >> 8], 1);
        atomicAdd(&hs[src[e] >> 8], 1);
    }
    __syncthreads();
    for (int i = t; i < NBUCK; i += 256) {
        int c = hd[i];
        hd[i] = c ? atomicAdd(&cursorD[i], c) : 0;
        c = hs[i];
        hs[i] = c ? atomicAdd(&cursorS[i], c) : 0;
    }
    __syncthreads();
    for (int k = 0; k < 50; k++) {
        int e = base + k * 256 + t;
        int s = src[e], d = dst[e];
        int a = __float_as_int(attr[e]);
        int p = atomicAdd(&hd[d >> 8], 1);
        edsD[p] = make_int2((s << 8) | (d & 255), a);
        int q = atomicAdd(&hs[s >> 8], 1);
        edsS[q] = make_int2(s & 255, a);
    }
}

// Per-bucket weighted degree via LDS float atomics -> dinv
__global__ __launch_bounds__(256) void k_deg(const int2* __restrict__ edsS,
                                             const int* __restrict__ binBaseS,
                                             float* __restrict__ dinv) {
    __shared__ float degL[256];
    int b = blockIdx.x, t = threadIdx.x;
    degL[t] = 0.f;
    __syncthreads();
    int s0 = binBaseS[b], s1 = binBaseS[b + 1];
    for (int i = s0 + t; i < s1; i += 256) {
        int2 e = edsS[i];
        atomicAdd(&degL[e.x], __int_as_float(e.y));
    }
    __syncthreads();
    float d = degL[t];
    dinv[b * 256 + t] = d > 0.f ? rsqrtf(d) : 0.f;
}

// ---------------------------------------------------------------------------
// Per-bucket exact CSR. cedge weight = -attr * dinv[src] * dinv[dst] (full).
// ---------------------------------------------------------------------------
__global__ __launch_bounds__(256) void k_csr(const int2* __restrict__ edsD,
                                             const int* __restrict__ binBaseD,
                                             const float* __restrict__ dinvG,
                                             int* __restrict__ rowp,
                                             int2* __restrict__ cedge) {
    __shared__ int cntL[256];
    __shared__ int curL[256];
    __shared__ float dL[256];
    int b = blockIdx.x, t = threadIdx.x;
    cntL[t] = 0;
    dL[t] = dinvG[b * 256 + t];
    __syncthreads();
    int s0 = binBaseD[b], s1 = binBaseD[b + 1];
    for (int i = s0 + t; i < s1; i += 256) {
        atomicAdd(&cntL[edsD[i].x & 255], 1);
    }
    __syncthreads();
    int v = cntL[t];
    for (int o = 1; o < 256; o <<= 1) {
        int x = (t >= o) ? cntL[t - o] : 0;
        __syncthreads();
        cntL[t] += x;
        __syncthreads();
    }
    int excl = cntL[t] - v;
    curL[t] = s0 + excl;
    rowp[b * 256 + t] = s0 + excl;
    __syncthreads();
    for (int i = s0 + t; i < s1; i += 256) {
        int2 e = edsD[i];
        int dl = e.x & 255;
        int sg = e.x >> 8;
        float w = -__int_as_float(e.y) * dinvG[sg] * dL[dl];
        int p = atomicAdd(&curL[dl], 1);
        cedge[p] = make_int2(sg, __float_as_int(w));
    }
}

// ---------------------------------------------------------------------------
// x -> slot-major bf16 hi/lo tables: Xhi/Xlo[s][n][64], s = k>>6
// ---------------------------------------------------------------------------
__global__ __launch_bounds__(256) void k_cast(const float* __restrict__ x,
                                              ushortT* __restrict__ Xhi,
                                              ushortT* __restrict__ Xlo) {
    int i = blockIdx.x * 256 + threadIdx.x;   // [0, N*32)
    int n = i >> 5;
    int kq = (i & 31) * 4;
    float4 v = ((const float4*)x)[i];
    int s = kq >> 6, kk = kq & 63;
    size_t o = (size_t)s * N64 + (size_t)n * 64 + kk;
    ushort4 h, l;
    h.x = f2b(v.x); l.x = f2b(v.x - b2f(h.x));
    h.y = f2b(v.y); l.y = f2b(v.y - b2f(h.y));
    h.z = f2b(v.z); l.z = f2b(v.z - b2f(h.z));
    h.w = f2b(v.w); l.w = f2b(v.w - b2f(h.w));
    *(ushort4*)(Xhi + o) = h;
    *(ushort4*)(Xlo + o) = l;
}

// ---------------------------------------------------------------------------
// Weight prep: transposed [N][K] bf16 hi/lo tables.
// L1: [192][128] from w1 (cols: W0-W2 | W1 | W2). L2: [192][64] from w2.
// L3: [128][192] from w3 (K spans the 3 hops).
// ---------------------------------------------------------------------------
template <int L>
__global__ void k_wprep(const float* __restrict__ w, ushortT* __restrict__ Wth,
                        ushortT* __restrict__ Wtl) {
    int i = blockIdx.x * 256 + threadIdx.x;
    float v;
    if (L == 1) {
        if (i >= 192 * 128) return;
        int n = i / 128, k = i % 128;
        if (n < 64)       v = w[k * 64 + n] - w[16384 + k * 64 + n];
        else if (n < 128) v = w[8192 + k * 64 + (n - 64)];
        else              v = w[16384 + k * 64 + (n - 128)];
    } else if (L == 2) {
        if (i >= 192 * 64) return;
        int n = i / 64, k = i % 64;
        if (n < 64)       v = w[k * 64 + n] - w[8192 + k * 64 + n];
        else if (n < 128) v = w[4096 + k * 64 + (n - 64)];
        else              v = w[8192 + k * 64 + (n - 128)];
    } else {
        if (i >= 128 * 192) return;
        int n = i / 192, k = i % 192;
        v = w[(k >> 6) * 8192 + (k & 63) * 128 + n];
    }
    ushortT h = f2b(v);
    Wth[i] = h;
    Wtl[i] = f2b(v - b2f(h));
}

// ---------------------------------------------------------------------------
// MFMA GEMM: out[64 rows x 64 cols per block], A bf16 hi/lo slot-major
// tables ([K/64][N][64]), Wt bf16 hi/lo [NTOT][KTOT]. 4 waves, wave = 16x64.
// acc = Ahi*Whi + Alo*Whi + Ahi*Wlo  (~fp32 accuracy).
// MODE 0: blockIdx.y<2 -> fp32 out[n*128 + y*64 + c]; y==2 -> bf16 outb[n*64+c]
// MODE 1: fp32 out[n*128 + col] = relu(acc + bias[col])
// ---------------------------------------------------------------------------
template <int KTOT, int MODE>
__global__ __launch_bounds__(256) void k_mgemm(
    const ushortT* __restrict__ Ah0, const ushortT* __restrict__ Ah1,
    const ushortT* __restrict__ Ah2, const ushortT* __restrict__ Al0,
    const ushortT* __restrict__ Al1, const ushortT* __restrict__ Al2,
    const ushortT* __restrict__ Wth, const ushortT* __restrict__ Wtl,
    const float* __restrict__ bias, float* __restrict__ outf,
    ushortT* __restrict__ outb) {
    const ushortT* Ah[3] = {Ah0, Ah1, Ah2};
    const ushortT* Al[3] = {Al0, Al1, Al2};
    int lane = threadIdx.x & 63;
    int wv = threadIdx.x >> 6;
    int r0 = blockIdx.x * 64 + wv * 16;
    int cbase = blockIdx.y * 64;
    int m = lane & 15, q = lane >> 4;
    int arow = r0 + m;
    f32x4 acc[4];
#pragma unroll
    for (int ct = 0; ct < 4; ct++)
#pragma unroll
        for (int j = 0; j < 4; j++) acc[ct][j] = 0.f;

#pragma unroll
    for (int ks = 0; ks < KTOT / 32; ks++) {
        int k0 = ks * 32;
        int slot = k0 >> 6;
        int kk = (k0 & 63) + q * 8;
        bf16x8 ah = *(const bf16x8*)(Ah[slot] + (size_t)arow * 64 + kk);
        bf16x8 al = *(const bf16x8*)(Al[slot] + (size_t)arow * 64 + kk);
#pragma unroll
        for (int ct = 0; ct < 4; ct++) {
            int col = cbase + ct * 16 + m;
            bf16x8 bh = *(const bf16x8*)(Wth + (size_t)col * KTOT + k0 + q * 8);
            bf16x8 bl = *(const bf16x8*)(Wtl + (size_t)col * KTOT + k0 + q * 8);
            acc[ct] = __builtin_amdgcn_mfma_f32_16x16x32_bf16(ah, bh, acc[ct], 0, 0, 0);
            acc[ct] = __builtin_amdgcn_mfma_f32_16x16x32_bf16(al, bh, acc[ct], 0, 0, 0);
            acc[ct] = __builtin_amdgcn_mfma_f32_16x16x32_bf16(ah, bl, acc[ct], 0, 0, 0);
        }
    }
#pragma unroll
    for (int ct = 0; ct < 4; ct++) {
#pragma unroll
        for (int rg = 0; rg < 4; rg++) {
            int row = r0 + q * 4 + rg;
            int cl = ct * 16 + m;
            float v = acc[ct][rg];
            if (MODE == 0) {
                if (blockIdx.y < 2)
                    outf[(size_t)row * 128 + blockIdx.y * 64 + cl] = v;
                else
                    outb[(size_t)row * 64 + cl] = f2b(v);
            } else {
                int col = cbase + cl;
                outf[(size_t)row * 128 + col] = fmaxf(v + bias[col], 0.f);
            }
        }
    }
}

// ---------------------------------------------------------------------------
// SpMM: gathers bf16 rows (stride 64), fp32 acc, clamped unroll-8.
// MODE 0: r = acc          MODE 1: r = aux + 2*acc
// MODE 2: r = 2*acc - aux  MODE 3: r = relu(aux + acc + bias[lane])
// aux: fp32 (stride SA) or bf16 hi+lo pair (AUXB). Output: bf16 hi (+lo).
// ---------------------------------------------------------------------------
template <int MODE, int SA, bool AUXB, bool WLO>
__global__ __launch_bounds__(256) void k_spmm(const int* __restrict__ rowp,
                                              const int2* __restrict__ cedge,
                                              const ushortT* __restrict__ Xb,
                                              const float* __restrict__ auxF,
                                              const ushortT* __restrict__ auxH,
                                              const ushortT* __restrict__ auxL,
                                              const float* __restrict__ bias,
                                              ushortT* __restrict__ Yh,
                                              ushortT* __restrict__ Yl) {
    int node = blockIdx.x * 4 + (threadIdx.x >> 6);
    int lane = threadIdx.x & 63;
    int s = rowp[node], e = rowp[node + 1];
    float acc = 0.f;
    for (int i = s; i < e; i += 8) {
        int2 ed[8];
        float v[8];
#pragma unroll
        for (int u = 0; u < 8; u++) {
            int idx = min(i + u, e - 1);
            ed[u] = cedge[idx];
        }
#pragma unroll
        for (int u = 0; u < 8; u++) v[u] = b2f(Xb[(size_t)ed[u].x * 64 + lane]);
#pragma unroll
        for (int u = 0; u < 8; u++) {
            float w = (i + u < e) ? __int_as_float(ed[u].y) : 0.f;
            acc = fmaf(w, v[u], acc);
        }
    }
    float aux = 0.f;
    if (MODE != 0) {
        if (AUXB)
            aux = b2f(auxH[(size_t)node * 64 + lane]) + b2f(auxL[(size_t)node * 64 + lane]);
        else
            aux = auxF[(size_t)node * SA + lane];
    }
    float r;
    if (MODE == 0)      r = acc;
    else if (MODE == 1) r = aux + 2.f * acc;
    else if (MODE == 2) r = 2.f * acc - aux;
    else                r = fmaxf(aux + acc + bias[lane], 0.f);
    ushortT h = f2b(r);
    Yh[(size_t)node * 64 + lane] = h;
    if (WLO) Yl[(size_t)node * 64 + lane] = f2b(r - b2f(h));
}

// ---------------------------------------------------------------------------
// Pooling: 64 consecutive nodes per block (batch sorted -> run-length)
// ---------------------------------------------------------------------------
__global__ __launch_bounds__(128) void k_pool(const int* __restrict__ batch,
                                              const float* __restrict__ H3,
                                              float* __restrict__ pooled,
                                              float* __restrict__ gcnt) {
    int t = threadIdx.x;
    int n0 = blockIdx.x * 64;
    int g = batch[n0];
    float a = 0.f;
    int c = 0;
    for (int k = 0; k < 64; k++) {
        int gn = batch[n0 + k];
        if (gn != g) {
            atomicAdd(&pooled[(size_t)g * 128 + t], a);
            if (t == 0) atomicAdd(&gcnt[g], (float)c);
            g = gn; a = 0.f; c = 0;
        }
        a += H3[(size_t)(n0 + k) * 128 + t];
        c++;
    }
    atomicAdd(&pooled[(size_t)g * 128 + t], a);
    if (t == 0) atomicAdd(&gcnt[g], (float)c);
}

__global__ void k_final(const float* __restrict__ pooled, const float* __restrict__ gcnt,
                        const float* __restrict__ lin_w, const float* __restrict__ lin_b,
                        float* __restrict__ out) {
    int g = blockIdx.x * 4 + (threadIdx.x >> 6);
    int lane = threadIdx.x & 63;
    if (g >= N_GRAPHS) return;
    float inv = 1.f / fmaxf(gcnt[g], 1.f);
    float v0 = pooled[(size_t)g * 128 + lane] * inv;
    float v1 = pooled[(size_t)g * 128 + 64 + lane] * inv;
    float p0 = v0 * lin_w[lane * 2 + 0] + v1 * lin_w[(lane + 64) * 2 + 0];
    float p1 = v0 * lin_w[lane * 2 + 1] + v1 * lin_w[(lane + 64) * 2 + 1];
    for (int o = 32; o > 0; o >>= 1) {
        p0 += __shfl_down(p0, o);
        p1 += __shfl_down(p1, o);
    }
    if (lane == 0) {
        out[g * 2 + 0] = p0 + lin_b[0];
        out[g * 2 + 1] = p1 + lin_b[1];
    }
}

// ---------------------------------------------------------------------------
extern "C" void kernel_launch(void* const* d_in, const int* in_sizes, int n_in,
                              void* d_out, int out_size, void* d_ws, size_t ws_size,
                              hipStream_t stream) {
    const float* x     = (const float*)d_in[0];
    const int*   src   = (const int*)d_in[1];
    const int*   dst   = src + N_EDGES;
    const float* eattr = (const float*)d_in[2];
    const int*   batch = (const int*)d_in[3];
    const float* w1    = (const float*)d_in[4];
    const float* b1    = (const float*)d_in[5];
    const float* w2    = (const float*)d_in[6];
    const float* b2    = (const float*)d_in[7];
    const float* w3    = (const float*)d_in[8];
    const float* b3    = (const float*)d_in[9];
    const float* lin_w = (const float*)d_in[10];
    const float* lin_b = (const float*)d_in[11];
    float* out = (float*)d_out;

    char* ws = (char*)d_ws;
    size_t off = 0;
    auto alloc = [&](size_t bytes) -> char* {
        char* p = ws + off;
        off += (bytes + 255) & ~(size_t)255;
        return p;
    };
    int*   binCntD  = (int*)  alloc(NBUCK * 4 * 2);
    int*   binCntS  = binCntD + NBUCK;
    int*   binBaseD = (int*)  alloc((NBUCK + 1) * 4);
    int*   binBaseS = (int*)  alloc((NBUCK + 1) * 4);
    int*   cursorD  = (int*)  alloc(NBUCK * 4);
    int*   cursorS  = (int*)  alloc(NBUCK * 4);
    float* dinv     = (float*)alloc((size_t)N_NODES * 4);
    int*   rowp     = (int*)  alloc((size_t)(N_NODES + 1) * 4);
    ushortT* Wt1h   = (ushortT*)alloc(192 * 128 * 2);
    ushortT* Wt1l   = (ushortT*)alloc(192 * 128 * 2);
    ushortT* Wt2h   = (ushortT*)alloc(192 * 64 * 2);
    ushortT* Wt2l   = (ushortT*)alloc(192 * 64 * 2);
    ushortT* Wt3h   = (ushortT*)alloc(128 * 192 * 2);
    ushortT* Wt3l   = (ushortT*)alloc(128 * 192 * 2);
    float* pooled   = (float*)alloc((size_t)(N_GRAPHS * 128 + N_GRAPHS) * 4);
    float* gcnt     = pooled + (size_t)N_GRAPHS * 128;
    int2*  cedge    = (int2*) alloc((size_t)N_EDGES * 8);      // 26.2 MB
    char*  Buf1     = alloc((size_t)N_EDGES * 16);             // 52.4 MB
    char*  Buf2     = alloc((size_t)N_NODES * 128 * 4);        // 52.4 MB
    char*  Buf3     = alloc(4 * N64 * 2);                      // 52.4 MB

    // Buf1: edsD+edsS (build)  ->  Xhi/Xlo [2][N][64]  ->  GThi [3][N][64]
    int2* edsD = (int2*)Buf1;
    int2* edsS = edsD + N_EDGES;
    ushortT* Xhi  = (ushortT*)Buf1;
    ushortT* Xlo  = Xhi + 2 * N64;
    ushortT* GThi = (ushortT*)Buf1;          // slots 0,1,2 contiguous
    // Buf2: P fp32 [N][128] (P0c | P1)  ->  H3 fp32 [N][128]
    float* P  = (float*)Buf2;
    float* H3 = (float*)Buf2;
    // Buf3: G0 | Qhi | H1hi | H1lo ; GTlo slots alias regions 0,2,3
    ushortT* G0    = (ushortT*)Buf3;
    ushortT* Qhi   = G0 + N64;
    ushortT* H1hi  = G0 + 2 * N64;
    ushortT* H1lo  = G0 + 3 * N64;
    ushortT* GTlo0 = G0;      // written after G0's last read
    ushortT* GTlo1 = H1hi;    // written after H1hi's last read
    ushortT* GTlo2 = H1lo;    // written after H1lo's last read

    hipMemsetAsync(binCntD, 0, NBUCK * 4 * 2, stream);
    hipMemsetAsync(pooled, 0, (size_t)(N_GRAPHS * 128 + N_GRAPHS) * 4, stream);

    // ---- CSR build (atomic-light)
    k_binA<<<256, 256, 0, stream>>>(src, dst, binCntD, binCntS);
    k_scanBins<<<1, 128, 0, stream>>>(binCntD, binCntS, binBaseD, binBaseS,
                                      cursorD, cursorS, rowp);
    k_binB<<<256, 256, 0, stream>>>(src, dst, eattr, cursorD, cursorS, edsD, edsS);
    k_deg<<<NBUCK, 256, 0, stream>>>(edsS, binBaseS, dinv);
    k_csr<<<NBUCK, 256, 0, stream>>>(edsD, binBaseD, dinv, rowp, cedge);

    // ---- Prep: x cast (after eds consumed), weight transpose+split
    k_cast<<<N_NODES * 32 / 256, 256, 0, stream>>>(x, Xhi, Xlo);
    k_wprep<1><<<96, 256, 0, stream>>>(w1, Wt1h, Wt1l);
    k_wprep<2><<<48, 256, 0, stream>>>(w2, Wt2h, Wt2l);
    k_wprep<3><<<96, 256, 0, stream>>>(w3, Wt3h, Wt3l);

    // ---- Layer 1 (128 -> 64): P0c,P1 fp32 + P2 bf16 table (G0)
    k_mgemm<128, 0><<<dim3(1600, 3), 256, 0, stream>>>(
        Xhi, Xhi + N64, nullptr, Xlo, Xlo + N64, nullptr, Wt1h, Wt1l, nullptr, P, G0);
    // Q = P1 + 2*L*P2 -> Qhi
    k_spmm<1, 128, false, false><<<N_NODES / 4, 256, 0, stream>>>(
        rowp, cedge, G0, P + 64, nullptr, nullptr, nullptr, Qhi, nullptr);
    // H1 = relu(P0c + L*Q + b1) -> H1hi/H1lo
    k_spmm<3, 128, false, true><<<N_NODES / 4, 256, 0, stream>>>(
        rowp, cedge, Qhi, P, nullptr, nullptr, b1, H1hi, H1lo);

    // ---- Layer 2 (64 -> 64)
    k_mgemm<64, 0><<<dim3(1600, 3), 256, 0, stream>>>(
        H1hi, nullptr, nullptr, H1lo, nullptr, nullptr, Wt2h, Wt2l, nullptr, P, G0);
    k_spmm<1, 128, false, false><<<N_NODES / 4, 256, 0, stream>>>(
        rowp, cedge, G0, P + 64, nullptr, nullptr, nullptr, Qhi, nullptr);
    // T0 = relu(P0c + L*Q + b2) -> GThi[0]/GTlo[0]
    k_spmm<3, 128, false, true><<<N_NODES / 4, 256, 0, stream>>>(
        rowp, cedge, Qhi, P, nullptr, nullptr, b2, GThi, GTlo0);

    // ---- Layer 3 (64 -> 128), spmm-first
    // T1 = L*T0 -> GThi[1]/GTlo[1]
    k_spmm<0, 64, false, true><<<N_NODES / 4, 256, 0, stream>>>(
        rowp, cedge, GThi, nullptr, nullptr, nullptr, nullptr, GThi + N64, GTlo1);
    // T2 = 2*L*T1 - T0 -> GThi[2]/GTlo[2]  (Aux = T0 via hi+lo)
    k_spmm<2, 64, true, true><<<N_NODES / 4, 256, 0, stream>>>(
        rowp, cedge, GThi + N64, nullptr, GThi, GTlo0, nullptr, GThi + 2 * N64, GTlo2);
    // H3 = relu([T0|T1|T2] @ w3 + b3) -> H3 fp32
    k_mgemm<192, 1><<<dim3(1600, 2), 256, 0, stream>>>(
        GThi, GThi + N64, GThi + 2 * N64, GTlo0, GTlo1, GTlo2, Wt3h, Wt3l, b3, H3, nullptr);

    // ---- Pool + final linear
    k_pool<<<N_NODES / 64, 128, 0, stream>>>(batch, H3, pooled, gcnt);
    k_final<<<N_GRAPHS / 4, 256, 0, stream>>>(pooled, gcnt, lin_w, lin_b, out);
}

// Round 7
// 1076.211 us; speedup vs baseline: 1.4443x; 1.3530x over previous
//
#include <hip/hip_runtime.h>
#include <cstddef>
#include <cstdint>

#define N_NODES 102400
#define N_EDGES 3276800
#define N_GRAPHS 1024
#define NBUCK 400            // node >> 8 -> 400 buckets of 256 nodes
#define N64 ((size_t)N_NODES * 64)

typedef unsigned short ushortT;
typedef unsigned int uintT;
typedef __attribute__((ext_vector_type(8))) short bf16x8;
typedef __attribute__((ext_vector_type(4))) float f32x4;

__device__ __forceinline__ float b2f(ushortT h) {
    return __uint_as_float(((uintT)h) << 16);
}
__device__ __forceinline__ ushortT f2b(float f) {
    uintT u = __float_as_uint(f);
    uintT r = (u + 0x7fffu + ((u >> 16) & 1u)) >> 16;
    return (ushortT)r;
}

// ---------------------------------------------------------------------------
// Pass A: per-block LDS histograms of dst/src coarse buckets -> global counts
// ---------------------------------------------------------------------------
__global__ __launch_bounds__(256) void k_binA(const int* __restrict__ src,
                                              const int* __restrict__ dst,
                                              int* __restrict__ binCntD,
                                              int* __restrict__ binCntS) {
    __shared__ int hd[NBUCK], hs[NBUCK];
    int t = threadIdx.x;
    for (int i = t; i < NBUCK; i += 256) { hd[i] = 0; hs[i] = 0; }
    __syncthreads();
    int base = blockIdx.x * 12800;
    for (int k = 0; k < 50; k++) {
        int e = base + k * 256 + t;
        atomicAdd(&hd[dst[e] >> 8], 1);
        atomicAdd(&hs[src[e] >> 8], 1);
    }
    __syncthreads();
    for (int i = t; i < NBUCK; i += 256) {
        if (hd[i]) atomicAdd(&binCntD[i], hd[i]);
        if (hs[i]) atomicAdd(&binCntS[i], hs[i]);
    }
}

__global__ void k_scanBins(const int* __restrict__ binCntD, const int* __restrict__ binCntS,
                           int* __restrict__ binBaseD, int* __restrict__ binBaseS,
                           int* __restrict__ cursorD, int* __restrict__ cursorS,
                           int* __restrict__ rowp) {
    int t = threadIdx.x;
    if (t == 0) {
        int run = 0;
        for (int i = 0; i < NBUCK; i++) {
            binBaseD[i] = run; cursorD[i] = run; run += binCntD[i];
        }
        binBaseD[NBUCK] = run;
        rowp[N_NODES] = run;
    } else if (t == 64) {
        int run = 0;
        for (int i = 0; i < NBUCK; i++) {
            binBaseS[i] = run; cursorS[i] = run; run += binCntS[i];
        }
        binBaseS[NBUCK] = run;
    }
}

// ---------------------------------------------------------------------------
// Pass B: place edges into dst-bucket regions (edsD) and src-bucket regions
// (edsS). One global atomic per (block,bucket); per-edge via LDS cursors.
// edsD: x = (src<<8)|dstLow, y = attr bits.  edsS: x = srcLow, y = attr bits
// ---------------------------------------------------------------------------
__global__ __launch_bounds__(256) void k_binB(const int* __restrict__ src,
                                              const int* __restrict__ dst,
                                              const float* __restrict__ attr,
                                              int* __restrict__ cursorD,
                                              int* __restrict__ cursorS,
                                              int2* __restrict__ edsD,
                                              int2* __restrict__ edsS) {
    __shared__ int hd[NBUCK], hs[NBUCK];
    int t = threadIdx.x;
    for (int i = t; i < NBUCK; i += 256) { hd[i] = 0; hs[i] = 0; }
    __syncthreads();
    int base = blockIdx.x * 12800;
    for (int k = 0; k < 50; k++) {
        int e = base + k * 256 + t;
        atomicAdd(&hd[dst[e] >> 8], 1);
        atomicAdd(&hs[src[e] >> 8], 1);
    }
    __syncthreads();
    for (int i = t; i < NBUCK; i += 256) {
        int c = hd[i];
        hd[i] = c ? atomicAdd(&cursorD[i], c) : 0;
        c = hs[i];
        hs[i] = c ? atomicAdd(&cursorS[i], c) : 0;
    }
    __syncthreads();
    for (int k = 0; k < 50; k++) {
        int e = base + k * 256 + t;
        int s = src[e], d = dst[e];
        int a = __float_as_int(attr[e]);
        int p = atomicAdd(&hd[d >> 8], 1);
        edsD[p] = make_int2((s << 8) | (d & 255), a);
        int q = atomicAdd(&hs[s >> 8], 1);
        edsS[q] = make_int2(s & 255, a);
    }
}

// Per-bucket weighted degree via LDS float atomics -> dinv
__global__ __launch_bounds__(256) void k_deg(const int2* __restrict__ edsS,
                                             const int* __restrict__ binBaseS,
                                             float* __restrict__ dinv) {
    __shared__ float degL[256];
    int b = blockIdx.x, t = threadIdx.x;
    degL[t] = 0.f;
    __syncthreads();
    int s0 = binBaseS[b], s1 = binBaseS[b + 1];
    for (int i = s0 + t; i < s1; i += 256) {
        int2 e = edsS[i];
        atomicAdd(&degL[e.x], __int_as_float(e.y));
    }
    __syncthreads();
    float d = degL[t];
    dinv[b * 256 + t] = d > 0.f ? rsqrtf(d) : 0.f;
}

// ---------------------------------------------------------------------------
// Per-bucket exact CSR. cedge weight = -attr * dinv[src] * dinv[dst] (full).
// ---------------------------------------------------------------------------
__global__ __launch_bounds__(256) void k_csr(const int2* __restrict__ edsD,
                                             const int* __restrict__ binBaseD,
                                             const float* __restrict__ dinvG,
                                             int* __restrict__ rowp,
                                             int2* __restrict__ cedge) {
    __shared__ int cntL[256];
    __shared__ int curL[256];
    __shared__ float dL[256];
    int b = blockIdx.x, t = threadIdx.x;
    cntL[t] = 0;
    dL[t] = dinvG[b * 256 + t];
    __syncthreads();
    int s0 = binBaseD[b], s1 = binBaseD[b + 1];
    for (int i = s0 + t; i < s1; i += 256) {
        atomicAdd(&cntL[edsD[i].x & 255], 1);
    }
    __syncthreads();
    int v = cntL[t];
    for (int o = 1; o < 256; o <<= 1) {
        int x = (t >= o) ? cntL[t - o] : 0;
        __syncthreads();
        cntL[t] += x;
        __syncthreads();
    }
    int excl = cntL[t] - v;
    curL[t] = s0 + excl;
    rowp[b * 256 + t] = s0 + excl;
    __syncthreads();
    for (int i = s0 + t; i < s1; i += 256) {
        int2 e = edsD[i];
        int dl = e.x & 255;
        int sg = e.x >> 8;
        float w = -__int_as_float(e.y) * dinvG[sg] * dL[dl];
        int p = atomicAdd(&curL[dl], 1);
        cedge[p] = make_int2(sg, __float_as_int(w));
    }
}

// ---------------------------------------------------------------------------
// x -> slot-major bf16 hi/lo tables: Xhi/Xlo[s][n][64], s = k>>6
// ---------------------------------------------------------------------------
__global__ __launch_bounds__(256) void k_cast(const float* __restrict__ x,
                                              ushortT* __restrict__ Xhi,
                                              ushortT* __restrict__ Xlo) {
    int i = blockIdx.x * 256 + threadIdx.x;   // [0, N*32)
    int n = i >> 5;
    int kq = (i & 31) * 4;
    float4 v = ((const float4*)x)[i];
    int s = kq >> 6, kk = kq & 63;
    size_t o = (size_t)s * N64 + (size_t)n * 64 + kk;
    ushort4 h, l;
    h.x = f2b(v.x); l.x = f2b(v.x - b2f(h.x));
    h.y = f2b(v.y); l.y = f2b(v.y - b2f(h.y));
    h.z = f2b(v.z); l.z = f2b(v.z - b2f(h.z));
    h.w = f2b(v.w); l.w = f2b(v.w - b2f(h.w));
    *(ushort4*)(Xhi + o) = h;
    *(ushort4*)(Xlo + o) = l;
}

// ---------------------------------------------------------------------------
// Weight prep: transposed [N][K] bf16 hi/lo tables.
// ---------------------------------------------------------------------------
template <int L>
__global__ void k_wprep(const float* __restrict__ w, ushortT* __restrict__ Wth,
                        ushortT* __restrict__ Wtl) {
    int i = blockIdx.x * 256 + threadIdx.x;
    float v;
    if (L == 1) {
        if (i >= 192 * 128) return;
        int n = i / 128, k = i % 128;
        if (n < 64)       v = w[k * 64 + n] - w[16384 + k * 64 + n];
        else if (n < 128) v = w[8192 + k * 64 + (n - 64)];
        else              v = w[16384 + k * 64 + (n - 128)];
    } else if (L == 2) {
        if (i >= 192 * 64) return;
        int n = i / 64, k = i % 64;
        if (n < 64)       v = w[k * 64 + n] - w[8192 + k * 64 + n];
        else if (n < 128) v = w[4096 + k * 64 + (n - 64)];
        else              v = w[8192 + k * 64 + (n - 128)];
    } else {
        if (i >= 128 * 192) return;
        int n = i / 192, k = i % 192;
        v = w[(k >> 6) * 8192 + (k & 63) * 128 + n];
    }
    ushortT h = f2b(v);
    Wth[i] = h;
    Wtl[i] = f2b(v - b2f(h));
}

// ---------------------------------------------------------------------------
// MFMA GEMM: out[64 rows x 64 cols per block], A bf16 hi/lo slot-major
// tables ([K/64][N][64]), Wt bf16 hi/lo [NTOT][KTOT]. 4 waves, wave = 16x64.
// acc = Ahi*Whi + Alo*Whi + Ahi*Wlo  (~fp32 accuracy).
// MODE 0: blockIdx.y<2 -> fp32 out[n*128 + y*64 + c]; y==2 -> bf16 outb[n*64+c]
// MODE 1: fp32 out[n*128 + col] = relu(acc + bias[col])
// ---------------------------------------------------------------------------
template <int KTOT, int MODE>
__global__ __launch_bounds__(256) void k_mgemm(
    const ushortT* __restrict__ Ah0, const ushortT* __restrict__ Ah1,
    const ushortT* __restrict__ Ah2, const ushortT* __restrict__ Al0,
    const ushortT* __restrict__ Al1, const ushortT* __restrict__ Al2,
    const ushortT* __restrict__ Wth, const ushortT* __restrict__ Wtl,
    const float* __restrict__ bias, float* __restrict__ outf,
    ushortT* __restrict__ outb) {
    const ushortT* Ah[3] = {Ah0, Ah1, Ah2};
    const ushortT* Al[3] = {Al0, Al1, Al2};
    int lane = threadIdx.x & 63;
    int wv = threadIdx.x >> 6;
    int r0 = blockIdx.x * 64 + wv * 16;
    int cbase = blockIdx.y * 64;
    int m = lane & 15, q = lane >> 4;
    int arow = r0 + m;
    f32x4 acc[4];
#pragma unroll
    for (int ct = 0; ct < 4; ct++)
#pragma unroll
        for (int j = 0; j < 4; j++) acc[ct][j] = 0.f;

#pragma unroll
    for (int ks = 0; ks < KTOT / 32; ks++) {
        int k0 = ks * 32;
        int slot = k0 >> 6;
        int kk = (k0 & 63) + q * 8;
        bf16x8 ah = *(const bf16x8*)(Ah[slot] + (size_t)arow * 64 + kk);
        bf16x8 al = *(const bf16x8*)(Al[slot] + (size_t)arow * 64 + kk);
#pragma unroll
        for (int ct = 0; ct < 4; ct++) {
            int col = cbase + ct * 16 + m;
            bf16x8 bh = *(const bf16x8*)(Wth + (size_t)col * KTOT + k0 + q * 8);
            bf16x8 bl = *(const bf16x8*)(Wtl + (size_t)col * KTOT + k0 + q * 8);
            acc[ct] = __builtin_amdgcn_mfma_f32_16x16x32_bf16(ah, bh, acc[ct], 0, 0, 0);
            acc[ct] = __builtin_amdgcn_mfma_f32_16x16x32_bf16(al, bh, acc[ct], 0, 0, 0);
            acc[ct] = __builtin_amdgcn_mfma_f32_16x16x32_bf16(ah, bl, acc[ct], 0, 0, 0);
        }
    }
#pragma unroll
    for (int ct = 0; ct < 4; ct++) {
#pragma unroll
        for (int rg = 0; rg < 4; rg++) {
            int row = r0 + q * 4 + rg;
            int cl = ct * 16 + m;
            float v = acc[ct][rg];
            if (MODE == 0) {
                if (blockIdx.y < 2)
                    outf[(size_t)row * 128 + blockIdx.y * 64 + cl] = v;
                else
                    outb[(size_t)row * 64 + cl] = f2b(v);
            } else {
                int col = cbase + cl;
                outf[(size_t)row * 128 + col] = fmaxf(v + bias[col], 0.f);
            }
        }
    }
}

// ---------------------------------------------------------------------------
// SpMM, quarter-wave edge parallelism: 16 lanes per edge-row, each lane
// loads uint2 = 4 bf16 features. One gather inst covers 4 edges (512 B).
// q = lane>>4 selects the edge within a 4-group; f = (lane&15)*4 features.
// Cross-quarter shfl_xor(16,32) reduction; quarters 0/1 write Yh/Yl.
// MODE 0: r = acc          MODE 1: r = aux + 2*acc
// MODE 2: r = 2*acc - aux  MODE 3: r = relu(aux + acc + bias)
// ---------------------------------------------------------------------------
template <int MODE, int SA, bool AUXB, bool WLO>
__global__ __launch_bounds__(256) void k_spmm(const int* __restrict__ rowp,
                                              const int2* __restrict__ cedge,
                                              const ushortT* __restrict__ Xb,
                                              const float* __restrict__ auxF,
                                              const ushortT* __restrict__ auxH,
                                              const ushortT* __restrict__ auxL,
                                              const float* __restrict__ bias,
                                              ushortT* __restrict__ Yh,
                                              ushortT* __restrict__ Yl) {
    int node = blockIdx.x * 4 + (threadIdx.x >> 6);
    int lane = threadIdx.x & 63;
    int q = lane >> 4;          // edge slot within group of 4
    int f = (lane & 15) * 4;    // feature base
    int s = rowp[node], e = rowp[node + 1];
    const ushortT* Xf = Xb + f;
    float a0 = 0.f, a1 = 0.f, a2 = 0.f, a3 = 0.f;
    for (int i = s; i < e; i += 8) {
        int i0 = min(i + q, e - 1);
        int i1 = min(i + 4 + q, e - 1);
        int2 ed0 = cedge[i0];
        int2 ed1 = cedge[i1];
        float w0 = (i + q < e) ? __int_as_float(ed0.y) : 0.f;
        float w1 = (i + 4 + q < e) ? __int_as_float(ed1.y) : 0.f;
        uint2 u0 = *(const uint2*)(Xf + ((size_t)ed0.x << 6));
        uint2 u1 = *(const uint2*)(Xf + ((size_t)ed1.x << 6));
        a0 = fmaf(w0, __uint_as_float(u0.x << 16), a0);
        a1 = fmaf(w0, __uint_as_float(u0.x & 0xffff0000u), a1);
        a2 = fmaf(w0, __uint_as_float(u0.y << 16), a2);
        a3 = fmaf(w0, __uint_as_float(u0.y & 0xffff0000u), a3);
        a0 = fmaf(w1, __uint_as_float(u1.x << 16), a0);
        a1 = fmaf(w1, __uint_as_float(u1.x & 0xffff0000u), a1);
        a2 = fmaf(w1, __uint_as_float(u1.y << 16), a2);
        a3 = fmaf(w1, __uint_as_float(u1.y & 0xffff0000u), a3);
    }
    // reduce across the 4 quarters (xor lane bits 4 and 5)
    a0 += __shfl_xor(a0, 16); a0 += __shfl_xor(a0, 32);
    a1 += __shfl_xor(a1, 16); a1 += __shfl_xor(a1, 32);
    a2 += __shfl_xor(a2, 16); a2 += __shfl_xor(a2, 32);
    a3 += __shfl_xor(a3, 16); a3 += __shfl_xor(a3, 32);

    if (q == 0 || (WLO && q == 1)) {
        float x0 = 0.f, x1 = 0.f, x2 = 0.f, x3 = 0.f;
        if (MODE != 0) {
            if (AUXB) {
                ushort4 ha = *(const ushort4*)(auxH + (size_t)node * 64 + f);
                ushort4 la = *(const ushort4*)(auxL + (size_t)node * 64 + f);
                x0 = b2f(ha.x) + b2f(la.x);
                x1 = b2f(ha.y) + b2f(la.y);
                x2 = b2f(ha.z) + b2f(la.z);
                x3 = b2f(ha.w) + b2f(la.w);
            } else {
                float4 av = *(const float4*)(auxF + (size_t)node * SA + f);
                x0 = av.x; x1 = av.y; x2 = av.z; x3 = av.w;
            }
        }
        float r0, r1, r2, r3;
        if (MODE == 0)      { r0 = a0; r1 = a1; r2 = a2; r3 = a3; }
        else if (MODE == 1) { r0 = x0 + 2.f * a0; r1 = x1 + 2.f * a1;
                              r2 = x2 + 2.f * a2; r3 = x3 + 2.f * a3; }
        else if (MODE == 2) { r0 = 2.f * a0 - x0; r1 = 2.f * a1 - x1;
                              r2 = 2.f * a2 - x2; r3 = 2.f * a3 - x3; }
        else {
            float4 bv = *(const float4*)(bias + f);
            r0 = fmaxf(x0 + a0 + bv.x, 0.f);
            r1 = fmaxf(x1 + a1 + bv.y, 0.f);
            r2 = fmaxf(x2 + a2 + bv.z, 0.f);
            r3 = fmaxf(x3 + a3 + bv.w, 0.f);
        }
        ushort4 h;
        h.x = f2b(r0); h.y = f2b(r1); h.z = f2b(r2); h.w = f2b(r3);
        if (q == 0) {
            *(ushort4*)(Yh + (size_t)node * 64 + f) = h;
        } else {
            ushort4 l;
            l.x = f2b(r0 - b2f(h.x));
            l.y = f2b(r1 - b2f(h.y));
            l.z = f2b(r2 - b2f(h.z));
            l.w = f2b(r3 - b2f(h.w));
            *(ushort4*)(Yl + (size_t)node * 64 + f) = l;
        }
    }
}

// ---------------------------------------------------------------------------
// Pooling: 64 consecutive nodes per block (batch sorted -> run-length)
// ---------------------------------------------------------------------------
__global__ __launch_bounds__(128) void k_pool(const int* __restrict__ batch,
                                              const float* __restrict__ H3,
                                              float* __restrict__ pooled,
                                              float* __restrict__ gcnt) {
    int t = threadIdx.x;
    int n0 = blockIdx.x * 64;
    int g = batch[n0];
    float a = 0.f;
    int c = 0;
    for (int k = 0; k < 64; k++) {
        int gn = batch[n0 + k];
        if (gn != g) {
            atomicAdd(&pooled[(size_t)g * 128 + t], a);
            if (t == 0) atomicAdd(&gcnt[g], (float)c);
            g = gn; a = 0.f; c = 0;
        }
        a += H3[(size_t)(n0 + k) * 128 + t];
        c++;
    }
    atomicAdd(&pooled[(size_t)g * 128 + t], a);
    if (t == 0) atomicAdd(&gcnt[g], (float)c);
}

__global__ void k_final(const float* __restrict__ pooled, const float* __restrict__ gcnt,
                        const float* __restrict__ lin_w, const float* __restrict__ lin_b,
                        float* __restrict__ out) {
    int g = blockIdx.x * 4 + (threadIdx.x >> 6);
    int lane = threadIdx.x & 63;
    if (g >= N_GRAPHS) return;
    float inv = 1.f / fmaxf(gcnt[g], 1.f);
    float v0 = pooled[(size_t)g * 128 + lane] * inv;
    float v1 = pooled[(size_t)g * 128 + 64 + lane] * inv;
    float p0 = v0 * lin_w[lane * 2 + 0] + v1 * lin_w[(lane + 64) * 2 + 0];
    float p1 = v0 * lin_w[lane * 2 + 1] + v1 * lin_w[(lane + 64) * 2 + 1];
    for (int o = 32; o > 0; o >>= 1) {
        p0 += __shfl_down(p0, o);
        p1 += __shfl_down(p1, o);
    }
    if (lane == 0) {
        out[g * 2 + 0] = p0 + lin_b[0];
        out[g * 2 + 1] = p1 + lin_b[1];
    }
}

// ---------------------------------------------------------------------------
extern "C" void kernel_launch(void* const* d_in, const int* in_sizes, int n_in,
                              void* d_out, int out_size, void* d_ws, size_t ws_size,
                              hipStream_t stream) {
    const float* x     = (const float*)d_in[0];
    const int*   src   = (const int*)d_in[1];
    const int*   dst   = src + N_EDGES;
    const float* eattr = (const float*)d_in[2];
    const int*   batch = (const int*)d_in[3];
    const float* w1    = (const float*)d_in[4];
    const float* b1    = (const float*)d_in[5];
    const float* w2    = (const float*)d_in[6];
    const float* b2    = (const float*)d_in[7];
    const float* w3    = (const float*)d_in[8];
    const float* b3    = (const float*)d_in[9];
    const float* lin_w = (const float*)d_in[10];
    const float* lin_b = (const float*)d_in[11];
    float* out = (float*)d_out;

    char* ws = (char*)d_ws;
    size_t off = 0;
    auto alloc = [&](size_t bytes) -> char* {
        char* p = ws + off;
        off += (bytes + 255) & ~(size_t)255;
        return p;
    };
    int*   binCntD  = (int*)  alloc(NBUCK * 4 * 2);
    int*   binCntS  = binCntD + NBUCK;
    int*   binBaseD = (int*)  alloc((NBUCK + 1) * 4);
    int*   binBaseS = (int*)  alloc((NBUCK + 1) * 4);
    int*   cursorD  = (int*)  alloc(NBUCK * 4);
    int*   cursorS  = (int*)  alloc(NBUCK * 4);
    float* dinv     = (float*)alloc((size_t)N_NODES * 4);
    int*   rowp     = (int*)  alloc((size_t)(N_NODES + 1) * 4);
    ushortT* Wt1h   = (ushortT*)alloc(192 * 128 * 2);
    ushortT* Wt1l   = (ushortT*)alloc(192 * 128 * 2);
    ushortT* Wt2h   = (ushortT*)alloc(192 * 64 * 2);
    ushortT* Wt2l   = (ushortT*)alloc(192 * 64 * 2);
    ushortT* Wt3h   = (ushortT*)alloc(128 * 192 * 2);
    ushortT* Wt3l   = (ushortT*)alloc(128 * 192 * 2);
    float* pooled   = (float*)alloc((size_t)(N_GRAPHS * 128 + N_GRAPHS) * 4);
    float* gcnt     = pooled + (size_t)N_GRAPHS * 128;
    int2*  cedge    = (int2*) alloc((size_t)N_EDGES * 8);      // 26.2 MB
    char*  Buf1     = alloc((size_t)N_EDGES * 16);             // 52.4 MB
    char*  Buf2     = alloc((size_t)N_NODES * 128 * 4);        // 52.4 MB
    char*  Buf3     = alloc(4 * N64 * 2);                      // 52.4 MB

    // Buf1: edsD+edsS (build)  ->  Xhi/Xlo [2][N][64]  ->  GThi [3][N][64]
    int2* edsD = (int2*)Buf1;
    int2* edsS = edsD + N_EDGES;
    ushortT* Xhi  = (ushortT*)Buf1;
    ushortT* Xlo  = Xhi + 2 * N64;
    ushortT* GThi = (ushortT*)Buf1;          // slots 0,1,2 contiguous
    // Buf2: P fp32 [N][128] (P0c | P1)  ->  H3 fp32 [N][128]
    float* P  = (float*)Buf2;
    float* H3 = (float*)Buf2;
    // Buf3: G0 | Qhi | H1hi | H1lo ; GTlo slots alias regions 0,2,3
    ushortT* G0    = (ushortT*)Buf3;
    ushortT* Qhi   = G0 + N64;
    ushortT* H1hi  = G0 + 2 * N64;
    ushortT* H1lo  = G0 + 3 * N64;
    ushortT* GTlo0 = G0;      // written after G0's last read
    ushortT* GTlo1 = H1hi;    // written after H1hi's last read
    ushortT* GTlo2 = H1lo;    // written after H1lo's last read

    hipMemsetAsync(binCntD, 0, NBUCK * 4 * 2, stream);
    hipMemsetAsync(pooled, 0, (size_t)(N_GRAPHS * 128 + N_GRAPHS) * 4, stream);

    // ---- CSR build (atomic-light)
    k_binA<<<256, 256, 0, stream>>>(src, dst, binCntD, binCntS);
    k_scanBins<<<1, 128, 0, stream>>>(binCntD, binCntS, binBaseD, binBaseS,
                                      cursorD, cursorS, rowp);
    k_binB<<<256, 256, 0, stream>>>(src, dst, eattr, cursorD, cursorS, edsD, edsS);
    k_deg<<<NBUCK, 256, 0, stream>>>(edsS, binBaseS, dinv);
    k_csr<<<NBUCK, 256, 0, stream>>>(edsD, binBaseD, dinv, rowp, cedge);

    // ---- Prep: x cast (after eds consumed), weight transpose+split
    k_cast<<<N_NODES * 32 / 256, 256, 0, stream>>>(x, Xhi, Xlo);
    k_wprep<1><<<96, 256, 0, stream>>>(w1, Wt1h, Wt1l);
    k_wprep<2><<<48, 256, 0, stream>>>(w2, Wt2h, Wt2l);
    k_wprep<3><<<96, 256, 0, stream>>>(w3, Wt3h, Wt3l);

    // ---- Layer 1 (128 -> 64): P0c,P1 fp32 + P2 bf16 table (G0)
    k_mgemm<128, 0><<<dim3(1600, 3), 256, 0, stream>>>(
        Xhi, Xhi + N64, nullptr, Xlo, Xlo + N64, nullptr, Wt1h, Wt1l, nullptr, P, G0);
    // Q = P1 + 2*L*P2 -> Qhi
    k_spmm<1, 128, false, false><<<N_NODES / 4, 256, 0, stream>>>(
        rowp, cedge, G0, P + 64, nullptr, nullptr, nullptr, Qhi, nullptr);
    // H1 = relu(P0c + L*Q + b1) -> H1hi/H1lo
    k_spmm<3, 128, false, true><<<N_NODES / 4, 256, 0, stream>>>(
        rowp, cedge, Qhi, P, nullptr, nullptr, b1, H1hi, H1lo);

    // ---- Layer 2 (64 -> 64)
    k_mgemm<64, 0><<<dim3(1600, 3), 256, 0, stream>>>(
        H1hi, nullptr, nullptr, H1lo, nullptr, nullptr, Wt2h, Wt2l, nullptr, P, G0);
    k_spmm<1, 128, false, false><<<N_NODES / 4, 256, 0, stream>>>(
        rowp, cedge, G0, P + 64, nullptr, nullptr, nullptr, Qhi, nullptr);
    // T0 = relu(P0c + L*Q + b2) -> GThi[0]/GTlo[0]
    k_spmm<3, 128, false, true><<<N_NODES / 4, 256, 0, stream>>>(
        rowp, cedge, Qhi, P, nullptr, nullptr, b2, GThi, GTlo0);

    // ---- Layer 3 (64 -> 128), spmm-first
    // T1 = L*T0 -> GThi[1]/GTlo[1]
    k_spmm<0, 64, false, true><<<N_NODES / 4, 256, 0, stream>>>(
        rowp, cedge, GThi, nullptr, nullptr, nullptr, nullptr, GThi + N64, GTlo1);
    // T2 = 2*L*T1 - T0 -> GThi[2]/GTlo[2]  (Aux = T0 via hi+lo)
    k_spmm<2, 64, true, true><<<N_NODES / 4, 256, 0, stream>>>(
        rowp, cedge, GThi + N64, nullptr, GThi, GTlo0, nullptr, GThi + 2 * N64, GTlo2);
    // H3 = relu([T0|T1|T2] @ w3 + b3) -> H3 fp32
    k_mgemm<192, 1><<<dim3(1600, 2), 256, 0, stream>>>(
        GThi, GThi + N64, GThi + 2 * N64, GTlo0, GTlo1, GTlo2, Wt3h, Wt3l, b3, H3, nullptr);

    // ---- Pool + final linear
    k_pool<<<N_NODES / 64, 128, 0, stream>>>(batch, H3, pooled, gcnt);
    k_final<<<N_GRAPHS / 4, 256, 0, stream>>>(pooled, gcnt, lin_w, lin_b, out);
}